// Round 1
// baseline (1147.876 us; speedup 1.0000x reference)
//
#include <hip/hip_runtime.h>
#include <math.h>

#define EDIM 768
#define NSEQ 1024
#define NB 8
#define NH 12
#define DH 64

// ---------------------------------------------------------------------------
// fp32 GEMM: C[8192,768] = A[8192,768] @ W[768,768]
// 128x128 block tile, 256 threads, 8x8 micro-tile, KT=16.
// blockIdx.z selects (W,C) pair so QKV runs as one 3-deep launch.
// ---------------------------------------------------------------------------
__global__ __launch_bounds__(256)
void gemm3_f32(const float* __restrict__ A,
               const float* __restrict__ W0, const float* __restrict__ W1,
               const float* __restrict__ W2,
               float* __restrict__ C0, float* __restrict__ C1,
               float* __restrict__ C2)
{
    const int z = blockIdx.z;
    const float* __restrict__ W = (z == 0) ? W0 : (z == 1) ? W1 : W2;
    float* __restrict__ C       = (z == 0) ? C0 : (z == 1) ? C1 : C2;

    // A stored transposed in LDS (As[k][m]) so micro-tile reads are float4.
    // Pad 128 -> 132 floats: write bank pattern (4kk + r) is <=2-way (free).
    __shared__ float As[16][132];
    __shared__ float Bs[16][132];

    const int t  = threadIdx.x;
    const int tx = t & 15;      // output col group
    const int ty = t >> 4;      // output row group
    const int n0 = blockIdx.x * 128;
    const int m0 = blockIdx.y * 128;

    float acc[8][8];
#pragma unroll
    for (int i = 0; i < 8; i++)
#pragma unroll
        for (int j = 0; j < 8; j++) acc[i][j] = 0.f;

    for (int k0 = 0; k0 < EDIM; k0 += 16) {
        // stage A tile: 128 rows x 16 k, transposed into As[k][m]
#pragma unroll
        for (int i = 0; i < 8; i++) {
            int idx = i * 256 + t;          // 0..2047
            int kk = idx & 15, r = idx >> 4;
            As[kk][r] = A[(size_t)(m0 + r) * EDIM + (k0 + kk)];
        }
        // stage W tile: 16 k x 128 n (natural layout, coalesced)
#pragma unroll
        for (int i = 0; i < 8; i++) {
            int idx = i * 256 + t;
            int kk = idx >> 7, c = idx & 127;
            Bs[kk][c] = W[(size_t)(k0 + kk) * EDIM + (n0 + c)];
        }
        __syncthreads();

#pragma unroll
        for (int kk = 0; kk < 16; kk++) {
            float a[8], b[8];
            float4 a0 = *(const float4*)&As[kk][ty * 8];
            float4 a1 = *(const float4*)&As[kk][ty * 8 + 4];
            float4 b0 = *(const float4*)&Bs[kk][tx * 8];
            float4 b1 = *(const float4*)&Bs[kk][tx * 8 + 4];
            a[0]=a0.x; a[1]=a0.y; a[2]=a0.z; a[3]=a0.w;
            a[4]=a1.x; a[5]=a1.y; a[6]=a1.z; a[7]=a1.w;
            b[0]=b0.x; b[1]=b0.y; b[2]=b0.z; b[3]=b0.w;
            b[4]=b1.x; b[5]=b1.y; b[6]=b1.z; b[7]=b1.w;
#pragma unroll
            for (int i = 0; i < 8; i++)
#pragma unroll
                for (int j = 0; j < 8; j++)
                    acc[i][j] = fmaf(a[i], b[j], acc[i][j]);
        }
        __syncthreads();
    }

#pragma unroll
    for (int i = 0; i < 8; i++) {
        float* crow = C + (size_t)(m0 + ty * 8 + i) * EDIM + n0 + tx * 8;
        *(float4*)&crow[0] = make_float4(acc[i][0], acc[i][1], acc[i][2], acc[i][3]);
        *(float4*)&crow[4] = make_float4(acc[i][4], acc[i][5], acc[i][6], acc[i][7]);
    }
}

// ---------------------------------------------------------------------------
// Flash attention, fp32, per (b,h): Qh/Kh/Vh are [1024,64] row-major at
// base + b*N*E + h*N*DH (the reference's reshape(-1,H,N,d) head split).
// Block = 256 threads handles 64 Q rows; iterates 16 key tiles of 64.
// Thread (r = t>>2, cg = t&3): owns score cols {cg + 4j} and O dims
// [cg*16, cg*16+16) of row r. Online softmax in registers; P broadcast to
// sibling lanes via __shfl (no LDS round-trip, no extra barrier).
// Writes Hc in the CONCAT layout [b][n][h*64+d] ready for @WO.
// ---------------------------------------------------------------------------
__global__ __launch_bounds__(256)
void attn_flash(const float* __restrict__ Q, const float* __restrict__ K,
                const float* __restrict__ V, const float* __restrict__ Bm,
                float* __restrict__ Hc)
{
    const int rt = blockIdx.x;   // 0..15 query-row tile
    const int h  = blockIdx.y;   // 0..11
    const int b  = blockIdx.z;   // 0..7
    const int r0 = rt * 64;

    const size_t headoff = (size_t)b * (NSEQ * EDIM) + (size_t)h * (NSEQ * DH);
    const float* Qh = Q + headoff;
    const float* Kh = K + headoff;
    const float* Vh = V + headoff;
    const float* Bh = Bm + (size_t)h * NSEQ * NSEQ;

    __shared__ float Qs[64][68];
    __shared__ float Ks[64][68];
    __shared__ float Vs[64][68];

    const int t  = threadIdx.x;
    const int r  = t >> 2;   // 0..63 query row within tile
    const int cg = t & 3;    // 0..3 column/dim group

    // stage Q tile: contiguous 4096 floats
    {
        const float* src = Qh + (size_t)r0 * DH;
#pragma unroll
        for (int i = 0; i < 4; i++) {
            int idx = (i * 256 + t) * 4;
            *(float4*)&Qs[idx >> 6][idx & 63] = *(const float4*)&src[idx];
        }
    }

    float m = -1e30f, l = 0.f;
    float o[16];
#pragma unroll
    for (int i = 0; i < 16; i++) o[i] = 0.f;

    for (int kt = 0; kt < 16; kt++) {
        const int c0 = kt * 64;
        __syncthreads();   // previous tile's Ks/Vs reads complete
        {
            const float* srcK = Kh + (size_t)c0 * DH;
            const float* srcV = Vh + (size_t)c0 * DH;
#pragma unroll
            for (int i = 0; i < 4; i++) {
                int idx = (i * 256 + t) * 4;
                *(float4*)&Ks[idx >> 6][idx & 63] = *(const float4*)&srcK[idx];
                *(float4*)&Vs[idx >> 6][idx & 63] = *(const float4*)&srcV[idx];
            }
        }
        __syncthreads();

        // ---- S = Q K^T for this thread's 16 columns (c = cg + 4j) ----
        float s[16];
#pragma unroll
        for (int j = 0; j < 16; j++) s[j] = 0.f;
#pragma unroll
        for (int d = 0; d < 64; d += 4) {
            float4 q = *(const float4*)&Qs[r][d];
#pragma unroll
            for (int j = 0; j < 16; j++) {
                float4 kv = *(const float4*)&Ks[cg + 4 * j][d];
                s[j] = fmaf(q.x, kv.x, s[j]);
                s[j] = fmaf(q.y, kv.y, s[j]);
                s[j] = fmaf(q.z, kv.z, s[j]);
                s[j] = fmaf(q.w, kv.w, s[j]);
            }
        }
        // scale + additive bias
        const float* brow = Bh + (size_t)(r0 + r) * NSEQ + c0;
#pragma unroll
        for (int j = 0; j < 16; j++)
            s[j] = fmaf(s[j], 0.125f, brow[cg + 4 * j]);

        // ---- online softmax (row spread over 4 consecutive lanes) ----
        float mx = s[0];
#pragma unroll
        for (int j = 1; j < 16; j++) mx = fmaxf(mx, s[j]);
        mx = fmaxf(mx, __shfl_xor(mx, 1));
        mx = fmaxf(mx, __shfl_xor(mx, 2));
        float m_new = fmaxf(m, mx);
        float alpha = __expf(m - m_new);
        float ls = 0.f;
#pragma unroll
        for (int j = 0; j < 16; j++) { s[j] = __expf(s[j] - m_new); ls += s[j]; }
        ls += __shfl_xor(ls, 1);
        ls += __shfl_xor(ls, 2);
        l = l * alpha + ls;
        m = m_new;
#pragma unroll
        for (int i = 0; i < 16; i++) o[i] *= alpha;

        // ---- PV: o[dims cg*16..+15] += sum_c P[r][c] * V[c][dim] ----
        // P[r][c] lives in lane (r*4 | (c&3)), register s[c>>2]: shfl it.
#pragma unroll
        for (int cg2 = 0; cg2 < 4; cg2++) {
            const int src = (t & ~3) | cg2;
#pragma unroll
            for (int j = 0; j < 16; j++) {
                float p = __shfl(s[j], src);
                const int c = cg2 + 4 * j;
#pragma unroll
                for (int i4 = 0; i4 < 4; i4++) {
                    float4 v4 = *(const float4*)&Vs[c][cg * 16 + i4 * 4];
                    o[i4 * 4 + 0] = fmaf(p, v4.x, o[i4 * 4 + 0]);
                    o[i4 * 4 + 1] = fmaf(p, v4.y, o[i4 * 4 + 1]);
                    o[i4 * 4 + 2] = fmaf(p, v4.z, o[i4 * 4 + 2]);
                    o[i4 * 4 + 3] = fmaf(p, v4.w, o[i4 * 4 + 3]);
                }
            }
        }
    }

    // finalize + write concat layout [b][n][h*64 + dim]
    const float inv_l = 1.f / l;
    float* dst = Hc + (size_t)b * (NSEQ * EDIM) + (size_t)(r0 + r) * EDIM
               + h * DH + cg * 16;
#pragma unroll
    for (int i4 = 0; i4 < 4; i4++) {
        *(float4*)&dst[i4 * 4] = make_float4(o[i4 * 4 + 0] * inv_l,
                                             o[i4 * 4 + 1] * inv_l,
                                             o[i4 * 4 + 2] * inv_l,
                                             o[i4 * 4 + 3] * inv_l);
    }
}

// ---------------------------------------------------------------------------
extern "C" void kernel_launch(void* const* d_in, const int* in_sizes, int n_in,
                              void* d_out, int out_size, void* d_ws, size_t ws_size,
                              hipStream_t stream)
{
    const float* emb = (const float*)d_in[0];
    const float* Bm  = (const float*)d_in[1];
    const float* WQ  = (const float*)d_in[2];
    const float* WK  = (const float*)d_in[3];
    const float* WV  = (const float*)d_in[4];
    const float* WO  = (const float*)d_in[5];
    float* out = (float*)d_out;

    const size_t SZ = (size_t)NB * NSEQ * EDIM;   // 6,291,456 floats
    float* Q  = (float*)d_ws;                     // ws usage: 4*SZ*4B = 100.7 MB
    float* Kp = Q + SZ;
    float* Vp = Kp + SZ;
    float* Hc = Vp + SZ;

    // 1) fused QKV projection
    dim3 ggrid(EDIM / 128, (NB * NSEQ) / 128, 3);
    gemm3_f32<<<ggrid, dim3(256), 0, stream>>>(emb, WQ, WK, WV, Q, Kp, Vp);

    // 2) flash attention with additive bias
    dim3 agrid(NSEQ / 64, NH, NB);
    attn_flash<<<agrid, dim3(256), 0, stream>>>(Q, Kp, Vp, Bm, Hc);

    // 3) output projection
    dim3 ogrid(EDIM / 128, (NB * NSEQ) / 128, 1);
    gemm3_f32<<<ogrid, dim3(256), 0, stream>>>(Hc, WO, WO, WO, out, out, out);
}

// Round 3
// 426.651 us; speedup vs baseline: 2.6904x; 2.6904x over previous
//
#include <hip/hip_runtime.h>
#include <math.h>

#define EDIM 768
#define NSEQ 1024
#define NB 8
#define NH 12
#define DH 64

typedef __attribute__((ext_vector_type(8))) short bh8;       // 8 bf16 (4 VGPRs) MFMA frag
typedef __attribute__((ext_vector_type(4))) float f4;        // MFMA acc
typedef __attribute__((ext_vector_type(8))) unsigned short us8;
typedef __attribute__((ext_vector_type(4))) unsigned short us4;

#define MFMA(a, b, c) __builtin_amdgcn_mfma_f32_16x16x32_bf16((bh8)(a), (bh8)(b), (c), 0, 0, 0)

__device__ __forceinline__ unsigned short f2bf(float x) {
    union { float f; unsigned u; } v; v.f = x;
    unsigned r = v.u + 0x7fff + ((v.u >> 16) & 1);   // round-to-nearest-even
    return (unsigned short)(r >> 16);
}
__device__ __forceinline__ float bf2f(unsigned short b) {
    union { float f; unsigned u; } v; v.u = ((unsigned)b) << 16;
    return v.f;
}

// ---------------------------------------------------------------------------
// emb fp32 -> hi/lo bf16 (hi = rne(x), lo = rne(x - hi))
// ---------------------------------------------------------------------------
__global__ __launch_bounds__(256)
void conv_emb(const float* __restrict__ E, unsigned short* __restrict__ Eh,
              unsigned short* __restrict__ El)
{
    size_t idx = ((size_t)blockIdx.x * 256 + threadIdx.x) * 4;
    float4 v = *(const float4*)&E[idx];
    us4 h, l;
    h.x = f2bf(v.x); l.x = f2bf(v.x - bf2f(h.x));
    h.y = f2bf(v.y); l.y = f2bf(v.y - bf2f(h.y));
    h.z = f2bf(v.z); l.z = f2bf(v.z - bf2f(h.z));
    h.w = f2bf(v.w); l.w = f2bf(v.w - bf2f(h.w));
    *(us4*)&Eh[idx] = h;
    *(us4*)&El[idx] = l;
}

// ---------------------------------------------------------------------------
// W [768k][768n] fp32 -> Wt [768n][768k] hi/lo bf16 (transposed so the MFMA
// B-operand read (8 consecutive k for fixed n) is a contiguous 16B LDS read).
// z selects WQ/WK/WV/WO.
// ---------------------------------------------------------------------------
__global__ __launch_bounds__(256)
void conv_w(const float* __restrict__ W0, const float* __restrict__ W1,
            const float* __restrict__ W2, const float* __restrict__ W3,
            unsigned short* __restrict__ Wbase)
{
    const int z = blockIdx.z;
    const float* __restrict__ W = (z == 0) ? W0 : (z == 1) ? W1 : (z == 2) ? W2 : W3;
    unsigned short* __restrict__ Wh = Wbase + (size_t)z * 2 * (EDIM * EDIM);
    unsigned short* __restrict__ Wl = Wh + (EDIM * EDIM);

    __shared__ float T[64][65];
    const int t = threadIdx.x;
    const int n0 = blockIdx.x * 64, k0 = blockIdx.y * 64;

#pragma unroll
    for (int rr = 0; rr < 4; rr++) {
        int row = rr * 16 + (t >> 4);      // k within tile
        int c4  = (t & 15) * 4;            // n within tile
        float4 v = *(const float4*)&W[(size_t)(k0 + row) * EDIM + n0 + c4];
        T[row][c4 + 0] = v.x; T[row][c4 + 1] = v.y;
        T[row][c4 + 2] = v.z; T[row][c4 + 3] = v.w;
    }
    __syncthreads();
#pragma unroll
    for (int rr = 0; rr < 4; rr++) {
        int nn = rr * 16 + (t >> 4);       // n within tile
        int k4 = (t & 15) * 4;             // k within tile
        us4 h, l;
        float v0 = T[k4 + 0][nn], v1 = T[k4 + 1][nn],
              v2 = T[k4 + 2][nn], v3 = T[k4 + 3][nn];
        h.x = f2bf(v0); l.x = f2bf(v0 - bf2f(h.x));
        h.y = f2bf(v1); l.y = f2bf(v1 - bf2f(h.y));
        h.z = f2bf(v2); l.z = f2bf(v2 - bf2f(h.z));
        h.w = f2bf(v3); l.w = f2bf(v3 - bf2f(h.w));
        size_t o = (size_t)(n0 + nn) * EDIM + k0 + k4;
        *(us4*)&Wh[o] = h;
        *(us4*)&Wl[o] = l;
    }
}

// ---------------------------------------------------------------------------
// QKV projection: C[8192,768] = E[8192,768] @ W, split-bf16 3-term MFMA.
// NOTE head split semantics: reference reshape(-1,H,N,d) means the NATURAL
// row-major [8192,768] output, viewed flat per batch, IS the per-head layout:
//   head(b,h) base = b*N*E + h*65536, element [m][dd] at +m*64+dd.
// So Q/K write natural layout. V is additionally transposed per head:
//   flat nr*768+col = 64*g + dim with g = nr*12 + (col>>6);
//   h = g>>10, key = g&1023, dim = col&63  ->  Vt[(b,h,dim)][key].
// ---------------------------------------------------------------------------
__global__ __launch_bounds__(256)
void qkv_gemm(const unsigned short* __restrict__ Eh, const unsigned short* __restrict__ El,
              const unsigned short* __restrict__ Wbase,
              unsigned short* __restrict__ Qh, unsigned short* __restrict__ Ql,
              unsigned short* __restrict__ Kh, unsigned short* __restrict__ Kl,
              unsigned short* __restrict__ Vt)
{
    const int z = blockIdx.z;
    const unsigned short* __restrict__ Wh = Wbase + (size_t)z * 2 * (EDIM * EDIM);
    const unsigned short* __restrict__ Wl = Wh + (EDIM * EDIM);

    __shared__ unsigned short Ah[128][40], Al[128][40];   // [row][k]
    __shared__ unsigned short Bh[128][40], Bl[128][40];   // [n][k] (W pre-transposed)

    const int t = threadIdx.x;
    const int wave = t >> 6, lane = t & 63;
    const int quad = lane >> 4, l16 = lane & 15;
    const int wm = (wave >> 1) * 64, wn = (wave & 1) * 64;
    const int m0 = blockIdx.y * 128, n0 = blockIdx.x * 128;

    const int sr = t >> 1, ss = (t & 1) * 16;   // staging: row, 16-elem segment

    f4 acc[4][4];
#pragma unroll
    for (int i = 0; i < 4; i++)
#pragma unroll
        for (int j = 0; j < 4; j++) acc[i][j] = (f4){0.f, 0.f, 0.f, 0.f};

    for (int k0 = 0; k0 < EDIM; k0 += 32) {
        const size_t ao = (size_t)(m0 + sr) * EDIM + k0 + ss;
        const size_t bo = (size_t)(n0 + sr) * EDIM + k0 + ss;
        us8 a0 = *(const us8*)&Eh[ao], a1 = *(const us8*)&Eh[ao + 8];
        us8 a2 = *(const us8*)&El[ao], a3 = *(const us8*)&El[ao + 8];
        us8 b0 = *(const us8*)&Wh[bo], b1 = *(const us8*)&Wh[bo + 8];
        us8 b2 = *(const us8*)&Wl[bo], b3 = *(const us8*)&Wl[bo + 8];
        __syncthreads();
        *(us8*)&Ah[sr][ss] = a0; *(us8*)&Ah[sr][ss + 8] = a1;
        *(us8*)&Al[sr][ss] = a2; *(us8*)&Al[sr][ss + 8] = a3;
        *(us8*)&Bh[sr][ss] = b0; *(us8*)&Bh[sr][ss + 8] = b1;
        *(us8*)&Bl[sr][ss] = b2; *(us8*)&Bl[sr][ss + 8] = b3;
        __syncthreads();

        bh8 aH[4], aL[4], bH[4], bL[4];
#pragma unroll
        for (int mt = 0; mt < 4; mt++) {
            aH[mt] = *(const bh8*)&Ah[wm + mt * 16 + l16][quad * 8];
            aL[mt] = *(const bh8*)&Al[wm + mt * 16 + l16][quad * 8];
        }
#pragma unroll
        for (int nt = 0; nt < 4; nt++) {
            bH[nt] = *(const bh8*)&Bh[wn + nt * 16 + l16][quad * 8];
            bL[nt] = *(const bh8*)&Bl[wn + nt * 16 + l16][quad * 8];
        }
#pragma unroll
        for (int mt = 0; mt < 4; mt++)
#pragma unroll
            for (int nt = 0; nt < 4; nt++) {
                acc[mt][nt] = MFMA(aH[mt], bH[nt], acc[mt][nt]);
                acc[mt][nt] = MFMA(aH[mt], bL[nt], acc[mt][nt]);
                acc[mt][nt] = MFMA(aL[mt], bH[nt], acc[mt][nt]);
            }
    }

    // epilogue: C/D layout col=lane&15, row=quad*4+reg
#pragma unroll
    for (int mt = 0; mt < 4; mt++)
#pragma unroll
        for (int nt = 0; nt < 4; nt++)
#pragma unroll
            for (int r = 0; r < 4; r++) {
                int row = m0 + wm + mt * 16 + quad * 4 + r;
                int col = n0 + wn + nt * 16 + l16;
                float v = acc[mt][nt][r];
                if (z == 2) {
                    int bb = row >> 10, nr = row & 1023;
                    int g = nr * 12 + (col >> 6);          // 768 = 12*64
                    int hh = g >> 10, key = g & 1023, dim = col & 63;
                    Vt[(((size_t)(bb * NH + hh)) * DH + dim) * NSEQ + key] = f2bf(v);
                } else {
                    unsigned short h = f2bf(v);
                    unsigned short l = f2bf(v - bf2f(h));
                    size_t o = (size_t)row * EDIM + col;
                    if (z == 0) { Qh[o] = h; Ql[o] = l; }
                    else        { Kh[o] = h; Kl[o] = l; }
                }
            }
}

// ---------------------------------------------------------------------------
// Flash attention, MFMA. Per-head Q/K base = b*N*E + h*65536, [1024,64]
// row-major (the reshape(-1,H,N,d) chunk split). Block = 64 Q-rows; 4 waves,
// each owns 16 rows. 3-term split-bf16 QK^T; fp32 bias+scale; online softmax
// on C-layout frags; P -> bf16 -> LDS -> A-layout; PV 1-term bf16.
// Output Hc bf16 in concat layout [b*1024+row][h*64+dim] (the transpose).
// ---------------------------------------------------------------------------
__global__ __launch_bounds__(256)
void attn_mfma(const unsigned short* __restrict__ Qh, const unsigned short* __restrict__ Ql,
               const unsigned short* __restrict__ Kh, const unsigned short* __restrict__ Kl,
               const unsigned short* __restrict__ Vt, const float* __restrict__ Bm,
               unsigned short* __restrict__ Hc)
{
    const int rt = blockIdx.x, h = blockIdx.y, b = blockIdx.z;
    const int r0 = rt * 64;

    __shared__ unsigned short Qhs[64][72], Qls[64][72];
    __shared__ unsigned short Khs[64][72], Kls[64][72];
    __shared__ unsigned short Vts[64][72];          // [dim][key]
    __shared__ unsigned short Ps[4][16][72];        // per-wave P tile [row][key]

    const int t = threadIdx.x;
    const int wave = t >> 6, lane = t & 63;
    const int quad = lane >> 4, l16 = lane & 15;
    const int wr = wave * 16;

    const int srow = t >> 2, sseg = (t & 3) * 16;   // staging decomposition

    // per-head bases (chunk split: head h = contiguous 65536 elems of batch b)
    const size_t hb = (size_t)b * (NSEQ * EDIM) + (size_t)h * (NSEQ * DH);
    const size_t vb = (((size_t)(b * NH + h)) * DH) * NSEQ;

    // stage Q tile (rows r0..r0+63 of the per-head [1024,64] matrix)
    {
        const size_t qo = hb + (size_t)(r0 + srow) * DH + sseg;
        us8 q0 = *(const us8*)&Qh[qo], q1 = *(const us8*)&Qh[qo + 8];
        us8 q2 = *(const us8*)&Ql[qo], q3 = *(const us8*)&Ql[qo + 8];
        *(us8*)&Qhs[srow][sseg] = q0; *(us8*)&Qhs[srow][sseg + 8] = q1;
        *(us8*)&Qls[srow][sseg] = q2; *(us8*)&Qls[srow][sseg + 8] = q3;
    }

    float m[4] = {-3e38f, -3e38f, -3e38f, -3e38f};
    float lsum[4] = {0.f, 0.f, 0.f, 0.f};
    f4 o[4];
#pragma unroll
    for (int dt = 0; dt < 4; dt++) o[dt] = (f4){0.f, 0.f, 0.f, 0.f};

    bh8 qfh[2], qfl[2];
    const float* bb = Bm + ((size_t)h << 20) + ((size_t)(r0 + wr + quad * 4) << 10) + l16;

    for (int kt = 0; kt < 16; kt++) {
        const int c0 = kt * 64;
        // prefetch K/V tile into registers before the barrier
        const size_t ko = hb + (size_t)(c0 + srow) * DH + sseg;
        const size_t vo = vb + (size_t)srow * NSEQ + c0 + sseg;
        us8 k0v = *(const us8*)&Kh[ko], k1v = *(const us8*)&Kh[ko + 8];
        us8 k2v = *(const us8*)&Kl[ko], k3v = *(const us8*)&Kl[ko + 8];
        us8 v0v = *(const us8*)&Vt[vo], v1v = *(const us8*)&Vt[vo + 8];
        __syncthreads();   // previous tile fully consumed
        *(us8*)&Khs[srow][sseg] = k0v; *(us8*)&Khs[srow][sseg + 8] = k1v;
        *(us8*)&Kls[srow][sseg] = k2v; *(us8*)&Kls[srow][sseg + 8] = k3v;
        *(us8*)&Vts[srow][sseg] = v0v; *(us8*)&Vts[srow][sseg + 8] = v1v;
        __syncthreads();

        if (kt == 0) {
#pragma unroll
            for (int ks = 0; ks < 2; ks++) {
                qfh[ks] = *(const bh8*)&Qhs[wr + l16][ks * 32 + quad * 8];
                qfl[ks] = *(const bh8*)&Qls[wr + l16][ks * 32 + quad * 8];
            }
        }

        // ---- scores: S[16 rows][64 keys] as 4 coltiles ----
        f4 s[4];
#pragma unroll
        for (int ct = 0; ct < 4; ct++) {
            bh8 kh0 = *(const bh8*)&Khs[ct * 16 + l16][quad * 8];
            bh8 kh1 = *(const bh8*)&Khs[ct * 16 + l16][32 + quad * 8];
            bh8 kl0 = *(const bh8*)&Kls[ct * 16 + l16][quad * 8];
            bh8 kl1 = *(const bh8*)&Kls[ct * 16 + l16][32 + quad * 8];
            f4 a = (f4){0.f, 0.f, 0.f, 0.f};
            a = MFMA(qfh[0], kh0, a); a = MFMA(qfh[1], kh1, a);
            a = MFMA(qfl[0], kh0, a); a = MFMA(qfl[1], kh1, a);
            a = MFMA(qfh[0], kl0, a); a = MFMA(qfh[1], kl1, a);
            s[ct] = a;
        }
        // scale + bias (fp32)
#pragma unroll
        for (int ct = 0; ct < 4; ct++)
#pragma unroll
            for (int r = 0; r < 4; r++)
                s[ct][r] = fmaf(s[ct][r], 0.125f, bb[(size_t)r * NSEQ + c0 + ct * 16]);

        // ---- online softmax (row state replicated across the 16 col-lanes) ----
        float alpha[4];
#pragma unroll
        for (int r = 0; r < 4; r++) {
            float mx = fmaxf(fmaxf(s[0][r], s[1][r]), fmaxf(s[2][r], s[3][r]));
            mx = fmaxf(mx, __shfl_xor(mx, 1));
            mx = fmaxf(mx, __shfl_xor(mx, 2));
            mx = fmaxf(mx, __shfl_xor(mx, 4));
            mx = fmaxf(mx, __shfl_xor(mx, 8));
            float mn = fmaxf(m[r], mx);
            alpha[r] = __expf(m[r] - mn);
            m[r] = mn;
        }
#pragma unroll
        for (int ct = 0; ct < 4; ct++)
#pragma unroll
            for (int r = 0; r < 4; r++)
                s[ct][r] = __expf(s[ct][r] - m[r]);
#pragma unroll
        for (int r = 0; r < 4; r++) {
            float ls = s[0][r] + s[1][r] + s[2][r] + s[3][r];
            ls += __shfl_xor(ls, 1);
            ls += __shfl_xor(ls, 2);
            ls += __shfl_xor(ls, 4);
            ls += __shfl_xor(ls, 8);
            lsum[r] = lsum[r] * alpha[r] + ls;
        }
#pragma unroll
        for (int dt = 0; dt < 4; dt++)
#pragma unroll
            for (int r = 0; r < 4; r++) o[dt][r] *= alpha[r];

        // ---- P -> bf16 -> LDS (C-layout -> A-layout transform) ----
        // wave-internal RAW: DS ops from one wave execute in order.
#pragma unroll
        for (int ct = 0; ct < 4; ct++)
#pragma unroll
            for (int r = 0; r < 4; r++)
                Ps[wave][quad * 4 + r][ct * 16 + l16] = f2bf(s[ct][r]);

        bh8 p0 = *(const bh8*)&Ps[wave][l16][quad * 8];
        bh8 p1 = *(const bh8*)&Ps[wave][l16][32 + quad * 8];
#pragma unroll
        for (int dt = 0; dt < 4; dt++) {
            bh8 v0 = *(const bh8*)&Vts[dt * 16 + l16][quad * 8];
            bh8 v1 = *(const bh8*)&Vts[dt * 16 + l16][32 + quad * 8];
            o[dt] = MFMA(p0, v0, o[dt]);
            o[dt] = MFMA(p1, v1, o[dt]);
        }
    }

    // epilogue: Hc bf16, concat layout [b][row][h*64+dim] (the 0,2,1,3 transpose)
#pragma unroll
    for (int r = 0; r < 4; r++) lsum[r] = 1.f / lsum[r];
#pragma unroll
    for (int dt = 0; dt < 4; dt++)
#pragma unroll
        for (int r = 0; r < 4; r++) {
            int row = r0 + wr + quad * 4 + r;
            int col = h * DH + dt * 16 + l16;
            Hc[(size_t)(b * NSEQ + row) * EDIM + col] = f2bf(o[dt][r] * lsum[r]);
        }
}

// ---------------------------------------------------------------------------
// Output projection: out[8192,768] = Hc_bf16 @ WO (1-term bf16 MFMA, fp32 out)
// ---------------------------------------------------------------------------
__global__ __launch_bounds__(256)
void out_gemm(const unsigned short* __restrict__ A, const unsigned short* __restrict__ Wh,
              float* __restrict__ C)
{
    __shared__ unsigned short Ah[128][40];
    __shared__ unsigned short Bh[128][40];

    const int t = threadIdx.x;
    const int wave = t >> 6, lane = t & 63;
    const int quad = lane >> 4, l16 = lane & 15;
    const int wm = (wave >> 1) * 64, wn = (wave & 1) * 64;
    const int m0 = blockIdx.y * 128, n0 = blockIdx.x * 128;
    const int sr = t >> 1, ss = (t & 1) * 16;

    f4 acc[4][4];
#pragma unroll
    for (int i = 0; i < 4; i++)
#pragma unroll
        for (int j = 0; j < 4; j++) acc[i][j] = (f4){0.f, 0.f, 0.f, 0.f};

    for (int k0 = 0; k0 < EDIM; k0 += 32) {
        const size_t ao = (size_t)(m0 + sr) * EDIM + k0 + ss;
        const size_t bo = (size_t)(n0 + sr) * EDIM + k0 + ss;
        us8 a0 = *(const us8*)&A[ao], a1 = *(const us8*)&A[ao + 8];
        us8 b0 = *(const us8*)&Wh[bo], b1 = *(const us8*)&Wh[bo + 8];
        __syncthreads();
        *(us8*)&Ah[sr][ss] = a0; *(us8*)&Ah[sr][ss + 8] = a1;
        *(us8*)&Bh[sr][ss] = b0; *(us8*)&Bh[sr][ss + 8] = b1;
        __syncthreads();

        bh8 aF[4], bF[4];
#pragma unroll
        for (int mt = 0; mt < 4; mt++)
            aF[mt] = *(const bh8*)&Ah[wm + mt * 16 + l16][quad * 8];
#pragma unroll
        for (int nt = 0; nt < 4; nt++)
            bF[nt] = *(const bh8*)&Bh[wn + nt * 16 + l16][quad * 8];
#pragma unroll
        for (int mt = 0; mt < 4; mt++)
#pragma unroll
            for (int nt = 0; nt < 4; nt++)
                acc[mt][nt] = MFMA(aF[mt], bF[nt], acc[mt][nt]);
    }

#pragma unroll
    for (int mt = 0; mt < 4; mt++)
#pragma unroll
        for (int nt = 0; nt < 4; nt++)
#pragma unroll
            for (int r = 0; r < 4; r++) {
                int row = m0 + wm + mt * 16 + quad * 4 + r;
                int col = n0 + wn + nt * 16 + l16;
                C[(size_t)row * EDIM + col] = acc[mt][nt][r];
            }
}

// ---------------------------------------------------------------------------
extern "C" void kernel_launch(void* const* d_in, const int* in_sizes, int n_in,
                              void* d_out, int out_size, void* d_ws, size_t ws_size,
                              hipStream_t stream)
{
    const float* emb = (const float*)d_in[0];
    const float* Bm  = (const float*)d_in[1];
    const float* WQ  = (const float*)d_in[2];
    const float* WK  = (const float*)d_in[3];
    const float* WV  = (const float*)d_in[4];
    const float* WO  = (const float*)d_in[5];
    float* out = (float*)d_out;

    const size_t SZ = (size_t)NB * NSEQ * EDIM;        // 6,291,456 elements
    const size_t WSZ = (size_t)EDIM * EDIM;            // 589,824

    unsigned short* p  = (unsigned short*)d_ws;
    unsigned short* Eh = p;                  p += SZ;   // later reused as Hc
    unsigned short* El = p;                  p += SZ;
    unsigned short* Wb = p;                  p += 8 * WSZ;  // WQ h/l, WK h/l, WV h/l, WO h/l
    unsigned short* Qh = p;                  p += SZ;
    unsigned short* Ql = p;                  p += SZ;
    unsigned short* Kh = p;                  p += SZ;
    unsigned short* Kl = p;                  p += SZ;
    unsigned short* Vt = p;                  p += SZ;
    unsigned short* Hc = Eh;                 // alias: emb-hi dead after qkv_gemm

    // 1) conversions
    conv_emb<<<dim3(SZ / (256 * 4)), dim3(256), 0, stream>>>(emb, Eh, El);
    conv_w<<<dim3(EDIM / 64, EDIM / 64, 4), dim3(256), 0, stream>>>(WQ, WK, WV, WO, Wb);

    // 2) QKV projection (3-term split-bf16 MFMA)
    qkv_gemm<<<dim3(EDIM / 128, (NB * NSEQ) / 128, 3), dim3(256), 0, stream>>>(
        Eh, El, Wb, Qh, Ql, Kh, Kl, Vt);

    // 3) flash attention (MFMA scores + PV)
    attn_mfma<<<dim3(NSEQ / 64, NH, NB), dim3(256), 0, stream>>>(
        Qh, Ql, Kh, Kl, Vt, Bm, Hc);

    // 4) output projection (1-term bf16 MFMA)
    out_gemm<<<dim3(EDIM / 128, (NB * NSEQ) / 128), dim3(256), 0, stream>>>(
        Hc, Wb + 6 * WSZ, out);
}

// Round 4
// 418.555 us; speedup vs baseline: 2.7425x; 1.0193x over previous
//
#include <hip/hip_runtime.h>
#include <math.h>

#define EDIM 768
#define NSEQ 1024
#define NB 8
#define NH 12
#define DH 64

typedef __attribute__((ext_vector_type(8))) short bh8;       // 8 bf16 (4 VGPRs) MFMA frag
typedef __attribute__((ext_vector_type(4))) float f4;        // MFMA acc
typedef __attribute__((ext_vector_type(8))) unsigned short us8;
typedef __attribute__((ext_vector_type(4))) unsigned short us4;

#define MFMA(a, b, c) __builtin_amdgcn_mfma_f32_16x16x32_bf16((bh8)(a), (bh8)(b), (c), 0, 0, 0)

__device__ __forceinline__ unsigned short f2bf(float x) {
    union { float f; unsigned u; } v; v.f = x;
    unsigned r = v.u + 0x7fff + ((v.u >> 16) & 1);   // round-to-nearest-even
    return (unsigned short)(r >> 16);
}
__device__ __forceinline__ float bf2f(unsigned short b) {
    union { float f; unsigned u; } v; v.u = ((unsigned)b) << 16;
    return v.f;
}

// ---------------------------------------------------------------------------
// emb fp32 -> hi/lo bf16 (hi = rne(x), lo = rne(x - hi))
// ---------------------------------------------------------------------------
__global__ __launch_bounds__(256)
void conv_emb(const float* __restrict__ E, unsigned short* __restrict__ Eh,
              unsigned short* __restrict__ El)
{
    size_t idx = ((size_t)blockIdx.x * 256 + threadIdx.x) * 4;
    float4 v = *(const float4*)&E[idx];
    us4 h, l;
    h.x = f2bf(v.x); l.x = f2bf(v.x - bf2f(h.x));
    h.y = f2bf(v.y); l.y = f2bf(v.y - bf2f(h.y));
    h.z = f2bf(v.z); l.z = f2bf(v.z - bf2f(h.z));
    h.w = f2bf(v.w); l.w = f2bf(v.w - bf2f(h.w));
    *(us4*)&Eh[idx] = h;
    *(us4*)&El[idx] = l;
}

// ---------------------------------------------------------------------------
// W [768k][768n] fp32 -> Wt [768n][768k] hi/lo bf16 (transposed).
// ---------------------------------------------------------------------------
__global__ __launch_bounds__(256)
void conv_w(const float* __restrict__ W0, const float* __restrict__ W1,
            const float* __restrict__ W2, const float* __restrict__ W3,
            unsigned short* __restrict__ Wbase)
{
    const int z = blockIdx.z;
    const float* __restrict__ W = (z == 0) ? W0 : (z == 1) ? W1 : (z == 2) ? W2 : W3;
    unsigned short* __restrict__ Wh = Wbase + (size_t)z * 2 * (EDIM * EDIM);
    unsigned short* __restrict__ Wl = Wh + (EDIM * EDIM);

    __shared__ float T[64][65];
    const int t = threadIdx.x;
    const int n0 = blockIdx.x * 64, k0 = blockIdx.y * 64;

#pragma unroll
    for (int rr = 0; rr < 4; rr++) {
        int row = rr * 16 + (t >> 4);      // k within tile
        int c4  = (t & 15) * 4;            // n within tile
        float4 v = *(const float4*)&W[(size_t)(k0 + row) * EDIM + n0 + c4];
        T[row][c4 + 0] = v.x; T[row][c4 + 1] = v.y;
        T[row][c4 + 2] = v.z; T[row][c4 + 3] = v.w;
    }
    __syncthreads();
#pragma unroll
    for (int rr = 0; rr < 4; rr++) {
        int nn = rr * 16 + (t >> 4);       // n within tile
        int k4 = (t & 15) * 4;             // k within tile
        us4 h, l;
        float v0 = T[k4 + 0][nn], v1 = T[k4 + 1][nn],
              v2 = T[k4 + 2][nn], v3 = T[k4 + 3][nn];
        h.x = f2bf(v0); l.x = f2bf(v0 - bf2f(h.x));
        h.y = f2bf(v1); l.y = f2bf(v1 - bf2f(h.y));
        h.z = f2bf(v2); l.z = f2bf(v2 - bf2f(h.z));
        h.w = f2bf(v3); l.w = f2bf(v3 - bf2f(h.w));
        size_t o = (size_t)(n0 + nn) * EDIM + k0 + k4;
        *(us4*)&Wh[o] = h;
        *(us4*)&Wl[o] = l;
    }
}

// ---------------------------------------------------------------------------
// QKV projection, split-bf16 MFMA. Quad-major LDS layout: X[quad][row][8]
// so frag reads (lanes l16 -> 16 consecutive 16B) and staging writes (two
// contiguous 512B streams per wave) are bank-conflict-free.
// z=0 (Q), z=1 (K): 3-term hi/lo. z=2 (V): 1-term (output is bf16 anyway).
// Head split is the reshape(-1,H,N,d) CHUNK split: Q/K natural layout;
// V scattered to per-head-transposed Vt[(b,h,dim)][key].
// ---------------------------------------------------------------------------
__global__ __launch_bounds__(256)
void qkv_gemm(const unsigned short* __restrict__ Eh, const unsigned short* __restrict__ El,
              const unsigned short* __restrict__ Wbase,
              unsigned short* __restrict__ Qh, unsigned short* __restrict__ Ql,
              unsigned short* __restrict__ Kh, unsigned short* __restrict__ Kl,
              unsigned short* __restrict__ Vt)
{
    const int z = blockIdx.z;
    const unsigned short* __restrict__ Wh = Wbase + (size_t)z * 2 * (EDIM * EDIM);
    const unsigned short* __restrict__ Wl = Wh + (EDIM * EDIM);

    __shared__ unsigned short Ahq[4][128][8], Alq[4][128][8];   // 8KB each
    __shared__ unsigned short Bhq[4][128][8], Blq[4][128][8];   // total 32KB

    const int t = threadIdx.x;
    const int wave = t >> 6, lane = t & 63;
    const int quad = lane >> 4, l16 = lane & 15;
    const int wm = (wave >> 1) * 64, wn = (wave & 1) * 64;
    const int m0 = blockIdx.y * 128, n0 = blockIdx.x * 128;

    const int sr = t >> 1, q0 = (t & 1) * 2;   // staging: row, first quad

    f4 acc[4][4];
#pragma unroll
    for (int i = 0; i < 4; i++)
#pragma unroll
        for (int j = 0; j < 4; j++) acc[i][j] = (f4){0.f, 0.f, 0.f, 0.f};

    for (int k0 = 0; k0 < EDIM; k0 += 32) {
        const size_t ao = (size_t)(m0 + sr) * EDIM + k0 + q0 * 8;
        const size_t bo = (size_t)(n0 + sr) * EDIM + k0 + q0 * 8;
        us8 a0 = *(const us8*)&Eh[ao], a1 = *(const us8*)&Eh[ao + 8];
        us8 b0 = *(const us8*)&Wh[bo], b1 = *(const us8*)&Wh[bo + 8];
        us8 a2, a3, b2, b3;
        if (z != 2) {
            a2 = *(const us8*)&El[ao]; a3 = *(const us8*)&El[ao + 8];
            b2 = *(const us8*)&Wl[bo]; b3 = *(const us8*)&Wl[bo + 8];
        }
        __syncthreads();
        *(us8*)&Ahq[q0][sr][0] = a0; *(us8*)&Ahq[q0 + 1][sr][0] = a1;
        *(us8*)&Bhq[q0][sr][0] = b0; *(us8*)&Bhq[q0 + 1][sr][0] = b1;
        if (z != 2) {
            *(us8*)&Alq[q0][sr][0] = a2; *(us8*)&Alq[q0 + 1][sr][0] = a3;
            *(us8*)&Blq[q0][sr][0] = b2; *(us8*)&Blq[q0 + 1][sr][0] = b3;
        }
        __syncthreads();

        bh8 aH[4], bH[4];
#pragma unroll
        for (int mt = 0; mt < 4; mt++)
            aH[mt] = *(const bh8*)&Ahq[quad][wm + mt * 16 + l16][0];
#pragma unroll
        for (int nt = 0; nt < 4; nt++)
            bH[nt] = *(const bh8*)&Bhq[quad][wn + nt * 16 + l16][0];

        if (z != 2) {
            bh8 aL[4], bL[4];
#pragma unroll
            for (int mt = 0; mt < 4; mt++)
                aL[mt] = *(const bh8*)&Alq[quad][wm + mt * 16 + l16][0];
#pragma unroll
            for (int nt = 0; nt < 4; nt++)
                bL[nt] = *(const bh8*)&Blq[quad][wn + nt * 16 + l16][0];
#pragma unroll
            for (int mt = 0; mt < 4; mt++)
#pragma unroll
                for (int nt = 0; nt < 4; nt++) {
                    acc[mt][nt] = MFMA(aH[mt], bH[nt], acc[mt][nt]);
                    acc[mt][nt] = MFMA(aH[mt], bL[nt], acc[mt][nt]);
                    acc[mt][nt] = MFMA(aL[mt], bH[nt], acc[mt][nt]);
                }
        } else {
#pragma unroll
            for (int mt = 0; mt < 4; mt++)
#pragma unroll
                for (int nt = 0; nt < 4; nt++)
                    acc[mt][nt] = MFMA(aH[mt], bH[nt], acc[mt][nt]);
        }
    }

    // epilogue: C/D layout col=lane&15, row=quad*4+reg
#pragma unroll
    for (int mt = 0; mt < 4; mt++)
#pragma unroll
        for (int nt = 0; nt < 4; nt++)
#pragma unroll
            for (int r = 0; r < 4; r++) {
                int row = m0 + wm + mt * 16 + quad * 4 + r;
                int col = n0 + wn + nt * 16 + l16;
                float v = acc[mt][nt][r];
                if (z == 2) {
                    int bb = row >> 10, nr = row & 1023;
                    int g = nr * 12 + (col >> 6);          // 768 = 12*64
                    int hh = g >> 10, key = g & 1023, dim = col & 63;
                    Vt[(((size_t)(bb * NH + hh)) * DH + dim) * NSEQ + key] = f2bf(v);
                } else {
                    unsigned short h = f2bf(v);
                    unsigned short l = f2bf(v - bf2f(h));
                    size_t o = (size_t)row * EDIM + col;
                    if (z == 0) { Qh[o] = h; Ql[o] = l; }
                    else        { Kh[o] = h; Kl[o] = l; }
                }
            }
}

// ---------------------------------------------------------------------------
// Flash attention, MFMA (unchanged from round 3 — correct at absmax 16).
// ---------------------------------------------------------------------------
__global__ __launch_bounds__(256)
void attn_mfma(const unsigned short* __restrict__ Qh, const unsigned short* __restrict__ Ql,
               const unsigned short* __restrict__ Kh, const unsigned short* __restrict__ Kl,
               const unsigned short* __restrict__ Vt, const float* __restrict__ Bm,
               unsigned short* __restrict__ Hc)
{
    const int rt = blockIdx.x, h = blockIdx.y, b = blockIdx.z;
    const int r0 = rt * 64;

    __shared__ unsigned short Qhs[64][72], Qls[64][72];
    __shared__ unsigned short Khs[64][72], Kls[64][72];
    __shared__ unsigned short Vts[64][72];          // [dim][key]
    __shared__ unsigned short Ps[4][16][72];        // per-wave P tile [row][key]

    const int t = threadIdx.x;
    const int wave = t >> 6, lane = t & 63;
    const int quad = lane >> 4, l16 = lane & 15;
    const int wr = wave * 16;

    const int srow = t >> 2, sseg = (t & 3) * 16;   // staging decomposition

    const size_t hb = (size_t)b * (NSEQ * EDIM) + (size_t)h * (NSEQ * DH);
    const size_t vb = (((size_t)(b * NH + h)) * DH) * NSEQ;

    // stage Q tile (rows r0..r0+63 of the per-head [1024,64] matrix)
    {
        const size_t qo = hb + (size_t)(r0 + srow) * DH + sseg;
        us8 q0 = *(const us8*)&Qh[qo], q1 = *(const us8*)&Qh[qo + 8];
        us8 q2 = *(const us8*)&Ql[qo], q3 = *(const us8*)&Ql[qo + 8];
        *(us8*)&Qhs[srow][sseg] = q0; *(us8*)&Qhs[srow][sseg + 8] = q1;
        *(us8*)&Qls[srow][sseg] = q2; *(us8*)&Qls[srow][sseg + 8] = q3;
    }

    float m[4] = {-3e38f, -3e38f, -3e38f, -3e38f};
    float lsum[4] = {0.f, 0.f, 0.f, 0.f};
    f4 o[4];
#pragma unroll
    for (int dt = 0; dt < 4; dt++) o[dt] = (f4){0.f, 0.f, 0.f, 0.f};

    bh8 qfh[2], qfl[2];
    const float* bb = Bm + ((size_t)h << 20) + ((size_t)(r0 + wr + quad * 4) << 10) + l16;

    for (int kt = 0; kt < 16; kt++) {
        const int c0 = kt * 64;
        // prefetch K/V tile into registers before the barrier
        const size_t ko = hb + (size_t)(c0 + srow) * DH + sseg;
        const size_t vo = vb + (size_t)srow * NSEQ + c0 + sseg;
        us8 k0v = *(const us8*)&Kh[ko], k1v = *(const us8*)&Kh[ko + 8];
        us8 k2v = *(const us8*)&Kl[ko], k3v = *(const us8*)&Kl[ko + 8];
        us8 v0v = *(const us8*)&Vt[vo], v1v = *(const us8*)&Vt[vo + 8];
        __syncthreads();   // previous tile fully consumed
        *(us8*)&Khs[srow][sseg] = k0v; *(us8*)&Khs[srow][sseg + 8] = k1v;
        *(us8*)&Kls[srow][sseg] = k2v; *(us8*)&Kls[srow][sseg + 8] = k3v;
        *(us8*)&Vts[srow][sseg] = v0v; *(us8*)&Vts[srow][sseg + 8] = v1v;
        __syncthreads();

        if (kt == 0) {
#pragma unroll
            for (int ks = 0; ks < 2; ks++) {
                qfh[ks] = *(const bh8*)&Qhs[wr + l16][ks * 32 + quad * 8];
                qfl[ks] = *(const bh8*)&Qls[wr + l16][ks * 32 + quad * 8];
            }
        }

        // ---- scores: S[16 rows][64 keys] as 4 coltiles ----
        f4 s[4];
#pragma unroll
        for (int ct = 0; ct < 4; ct++) {
            bh8 kh0 = *(const bh8*)&Khs[ct * 16 + l16][quad * 8];
            bh8 kh1 = *(const bh8*)&Khs[ct * 16 + l16][32 + quad * 8];
            bh8 kl0 = *(const bh8*)&Kls[ct * 16 + l16][quad * 8];
            bh8 kl1 = *(const bh8*)&Kls[ct * 16 + l16][32 + quad * 8];
            f4 a = (f4){0.f, 0.f, 0.f, 0.f};
            a = MFMA(qfh[0], kh0, a); a = MFMA(qfh[1], kh1, a);
            a = MFMA(qfl[0], kh0, a); a = MFMA(qfl[1], kh1, a);
            a = MFMA(qfh[0], kl0, a); a = MFMA(qfh[1], kl1, a);
            s[ct] = a;
        }
        // scale + bias (fp32)
#pragma unroll
        for (int ct = 0; ct < 4; ct++)
#pragma unroll
            for (int r = 0; r < 4; r++)
                s[ct][r] = fmaf(s[ct][r], 0.125f, bb[(size_t)r * NSEQ + c0 + ct * 16]);

        // ---- online softmax (row state replicated across the 16 col-lanes) ----
        float alpha[4];
#pragma unroll
        for (int r = 0; r < 4; r++) {
            float mx = fmaxf(fmaxf(s[0][r], s[1][r]), fmaxf(s[2][r], s[3][r]));
            mx = fmaxf(mx, __shfl_xor(mx, 1));
            mx = fmaxf(mx, __shfl_xor(mx, 2));
            mx = fmaxf(mx, __shfl_xor(mx, 4));
            mx = fmaxf(mx, __shfl_xor(mx, 8));
            float mn = fmaxf(m[r], mx);
            alpha[r] = __expf(m[r] - mn);
            m[r] = mn;
        }
#pragma unroll
        for (int ct = 0; ct < 4; ct++)
#pragma unroll
            for (int r = 0; r < 4; r++)
                s[ct][r] = __expf(s[ct][r] - m[r]);
#pragma unroll
        for (int r = 0; r < 4; r++) {
            float ls = s[0][r] + s[1][r] + s[2][r] + s[3][r];
            ls += __shfl_xor(ls, 1);
            ls += __shfl_xor(ls, 2);
            ls += __shfl_xor(ls, 4);
            ls += __shfl_xor(ls, 8);
            lsum[r] = lsum[r] * alpha[r] + ls;
        }
#pragma unroll
        for (int dt = 0; dt < 4; dt++)
#pragma unroll
            for (int r = 0; r < 4; r++) o[dt][r] *= alpha[r];

        // ---- P -> bf16 -> LDS (C-layout -> A-layout transform) ----
#pragma unroll
        for (int ct = 0; ct < 4; ct++)
#pragma unroll
            for (int r = 0; r < 4; r++)
                Ps[wave][quad * 4 + r][ct * 16 + l16] = f2bf(s[ct][r]);

        bh8 p0 = *(const bh8*)&Ps[wave][l16][quad * 8];
        bh8 p1 = *(const bh8*)&Ps[wave][l16][32 + quad * 8];
#pragma unroll
        for (int dt = 0; dt < 4; dt++) {
            bh8 v0 = *(const bh8*)&Vts[dt * 16 + l16][quad * 8];
            bh8 v1 = *(const bh8*)&Vts[dt * 16 + l16][32 + quad * 8];
            o[dt] = MFMA(p0, v0, o[dt]);
            o[dt] = MFMA(p1, v1, o[dt]);
        }
    }

    // epilogue: Hc bf16, concat layout [b][row][h*64+dim]
#pragma unroll
    for (int r = 0; r < 4; r++) lsum[r] = 1.f / lsum[r];
#pragma unroll
    for (int dt = 0; dt < 4; dt++)
#pragma unroll
        for (int r = 0; r < 4; r++) {
            int row = r0 + wr + quad * 4 + r;
            int col = h * DH + dt * 16 + l16;
            Hc[(size_t)(b * NSEQ + row) * EDIM + col] = f2bf(o[dt][r] * lsum[r]);
        }
}

// ---------------------------------------------------------------------------
// Output projection: out = Hc_bf16 @ WO, 1-term MFMA, quad-major LDS.
// ---------------------------------------------------------------------------
__global__ __launch_bounds__(256)
void out_gemm(const unsigned short* __restrict__ A, const unsigned short* __restrict__ Wh,
              float* __restrict__ C)
{
    __shared__ unsigned short Ahq[4][128][8];
    __shared__ unsigned short Bhq[4][128][8];

    const int t = threadIdx.x;
    const int wave = t >> 6, lane = t & 63;
    const int quad = lane >> 4, l16 = lane & 15;
    const int wm = (wave >> 1) * 64, wn = (wave & 1) * 64;
    const int m0 = blockIdx.y * 128, n0 = blockIdx.x * 128;
    const int sr = t >> 1, q0 = (t & 1) * 2;

    f4 acc[4][4];
#pragma unroll
    for (int i = 0; i < 4; i++)
#pragma unroll
        for (int j = 0; j < 4; j++) acc[i][j] = (f4){0.f, 0.f, 0.f, 0.f};

    for (int k0 = 0; k0 < EDIM; k0 += 32) {
        const size_t ao = (size_t)(m0 + sr) * EDIM + k0 + q0 * 8;
        const size_t bo = (size_t)(n0 + sr) * EDIM + k0 + q0 * 8;
        us8 a0 = *(const us8*)&A[ao], a1 = *(const us8*)&A[ao + 8];
        us8 b0 = *(const us8*)&Wh[bo], b1 = *(const us8*)&Wh[bo + 8];
        __syncthreads();
        *(us8*)&Ahq[q0][sr][0] = a0; *(us8*)&Ahq[q0 + 1][sr][0] = a1;
        *(us8*)&Bhq[q0][sr][0] = b0; *(us8*)&Bhq[q0 + 1][sr][0] = b1;
        __syncthreads();

        bh8 aF[4], bF[4];
#pragma unroll
        for (int mt = 0; mt < 4; mt++)
            aF[mt] = *(const bh8*)&Ahq[quad][wm + mt * 16 + l16][0];
#pragma unroll
        for (int nt = 0; nt < 4; nt++)
            bF[nt] = *(const bh8*)&Bhq[quad][wn + nt * 16 + l16][0];
#pragma unroll
        for (int mt = 0; mt < 4; mt++)
#pragma unroll
            for (int nt = 0; nt < 4; nt++)
                acc[mt][nt] = MFMA(aF[mt], bF[nt], acc[mt][nt]);
    }

#pragma unroll
    for (int mt = 0; mt < 4; mt++)
#pragma unroll
        for (int nt = 0; nt < 4; nt++)
#pragma unroll
            for (int r = 0; r < 4; r++) {
                int row = m0 + wm + mt * 16 + quad * 4 + r;
                int col = n0 + wn + nt * 16 + l16;
                C[(size_t)row * EDIM + col] = acc[mt][nt][r];
            }
}

// ---------------------------------------------------------------------------
extern "C" void kernel_launch(void* const* d_in, const int* in_sizes, int n_in,
                              void* d_out, int out_size, void* d_ws, size_t ws_size,
                              hipStream_t stream)
{
    const float* emb = (const float*)d_in[0];
    const float* Bm  = (const float*)d_in[1];
    const float* WQ  = (const float*)d_in[2];
    const float* WK  = (const float*)d_in[3];
    const float* WV  = (const float*)d_in[4];
    const float* WO  = (const float*)d_in[5];
    float* out = (float*)d_out;

    const size_t SZ = (size_t)NB * NSEQ * EDIM;        // 6,291,456 elements
    const size_t WSZ = (size_t)EDIM * EDIM;            // 589,824

    unsigned short* p  = (unsigned short*)d_ws;
    unsigned short* Eh = p;                  p += SZ;   // later reused as Hc
    unsigned short* El = p;                  p += SZ;
    unsigned short* Wb = p;                  p += 8 * WSZ;  // WQ h/l, WK h/l, WV h/l, WO h/l
    unsigned short* Qh = p;                  p += SZ;
    unsigned short* Ql = p;                  p += SZ;
    unsigned short* Kh = p;                  p += SZ;
    unsigned short* Kl = p;                  p += SZ;
    unsigned short* Vt = p;                  p += SZ;
    unsigned short* Hc = Eh;                 // alias: emb-hi dead after qkv_gemm

    // 1) conversions
    conv_emb<<<dim3(SZ / (256 * 4)), dim3(256), 0, stream>>>(emb, Eh, El);
    conv_w<<<dim3(EDIM / 64, EDIM / 64, 4), dim3(256), 0, stream>>>(WQ, WK, WV, WO, Wb);

    // 2) QKV projection (Q/K 3-term, V 1-term)
    qkv_gemm<<<dim3(EDIM / 128, (NB * NSEQ) / 128, 3), dim3(256), 0, stream>>>(
        Eh, El, Wb, Qh, Ql, Kh, Kl, Vt);

    // 3) flash attention (MFMA scores + PV)
    attn_mfma<<<dim3(NSEQ / 64, NH, NB), dim3(256), 0, stream>>>(
        Qh, Ql, Kh, Kl, Vt, Bm, Hc);

    // 4) output projection (1-term bf16 MFMA)
    out_gemm<<<dim3(EDIM / 128, (NB * NSEQ) / 128), dim3(256), 0, stream>>>(
        Hc, Wb + 6 * WSZ, out);
}

// Round 5
// 397.753 us; speedup vs baseline: 2.8859x; 1.0523x over previous
//
#include <hip/hip_runtime.h>
#include <math.h>

#define EDIM 768
#define NSEQ 1024
#define NB 8
#define NH 12
#define DH 64

typedef __attribute__((ext_vector_type(8))) short bh8;       // 8 bf16 (4 VGPRs) MFMA frag
typedef __attribute__((ext_vector_type(4))) float f4;        // MFMA acc
typedef __attribute__((ext_vector_type(8))) unsigned short us8;
typedef __attribute__((ext_vector_type(4))) unsigned short us4;

#define MFMA(a, b, c) __builtin_amdgcn_mfma_f32_16x16x32_bf16((bh8)(a), (bh8)(b), (c), 0, 0, 0)

__device__ __forceinline__ unsigned short f2bf(float x) {
    union { float f; unsigned u; } v; v.f = x;
    unsigned r = v.u + 0x7fff + ((v.u >> 16) & 1);   // round-to-nearest-even
    return (unsigned short)(r >> 16);
}
__device__ __forceinline__ float bf2f(unsigned short b) {
    union { float f; unsigned u; } v; v.u = ((unsigned)b) << 16;
    return v.f;
}

// ---------------------------------------------------------------------------
// emb fp32 -> hi/lo bf16
// ---------------------------------------------------------------------------
__global__ __launch_bounds__(256)
void conv_emb(const float* __restrict__ E, unsigned short* __restrict__ Eh,
              unsigned short* __restrict__ El)
{
    size_t idx = ((size_t)blockIdx.x * 256 + threadIdx.x) * 4;
    float4 v = *(const float4*)&E[idx];
    us4 h, l;
    h.x = f2bf(v.x); l.x = f2bf(v.x - bf2f(h.x));
    h.y = f2bf(v.y); l.y = f2bf(v.y - bf2f(h.y));
    h.z = f2bf(v.z); l.z = f2bf(v.z - bf2f(h.z));
    h.w = f2bf(v.w); l.w = f2bf(v.w - bf2f(h.w));
    *(us4*)&Eh[idx] = h;
    *(us4*)&El[idx] = l;
}

// ---------------------------------------------------------------------------
// W [768k][768n] fp32 -> Wt [768n][768k] hi/lo bf16 (transposed).
// ---------------------------------------------------------------------------
__global__ __launch_bounds__(256)
void conv_w(const float* __restrict__ W0, const float* __restrict__ W1,
            const float* __restrict__ W2, const float* __restrict__ W3,
            unsigned short* __restrict__ Wbase)
{
    const int z = blockIdx.z;
    const float* __restrict__ W = (z == 0) ? W0 : (z == 1) ? W1 : (z == 2) ? W2 : W3;
    unsigned short* __restrict__ Wh = Wbase + (size_t)z * 2 * (EDIM * EDIM);
    unsigned short* __restrict__ Wl = Wh + (EDIM * EDIM);

    __shared__ float T[64][65];
    const int t = threadIdx.x;
    const int n0 = blockIdx.x * 64, k0 = blockIdx.y * 64;

#pragma unroll
    for (int rr = 0; rr < 4; rr++) {
        int row = rr * 16 + (t >> 4);      // k within tile
        int c4  = (t & 15) * 4;            // n within tile
        float4 v = *(const float4*)&W[(size_t)(k0 + row) * EDIM + n0 + c4];
        T[row][c4 + 0] = v.x; T[row][c4 + 1] = v.y;
        T[row][c4 + 2] = v.z; T[row][c4 + 3] = v.w;
    }
    __syncthreads();
#pragma unroll
    for (int rr = 0; rr < 4; rr++) {
        int nn = rr * 16 + (t >> 4);       // n within tile
        int k4 = (t & 15) * 4;             // k within tile
        us4 h, l;
        float v0 = T[k4 + 0][nn], v1 = T[k4 + 1][nn],
              v2 = T[k4 + 2][nn], v3 = T[k4 + 3][nn];
        h.x = f2bf(v0); l.x = f2bf(v0 - bf2f(h.x));
        h.y = f2bf(v1); l.y = f2bf(v1 - bf2f(h.y));
        h.z = f2bf(v2); l.z = f2bf(v2 - bf2f(h.z));
        h.w = f2bf(v3); l.w = f2bf(v3 - bf2f(h.w));
        size_t o = (size_t)(n0 + nn) * EDIM + k0 + k4;
        *(us4*)&Wh[o] = h;
        *(us4*)&Wl[o] = l;
    }
}

// ---------------------------------------------------------------------------
// QKV projection, split-bf16 MFMA, quad-major LDS.
// XCD swizzle: dispatch round-robins blocks over 8 XCDs (xcd = bid&7), so we
// assign all 18 (n,z) siblings of an A-strip (same 128 rows) to ONE xcd slot:
// the strip's hi/lo A data (393 KB) is fetched once into that XCD's L2 and
// re-read 17x from L2 instead of HBM/L3.
// z=0 (Q), z=1 (K): 3-term hi/lo. z=2 (V): 1-term.
// ---------------------------------------------------------------------------
__global__ __launch_bounds__(256)
void qkv_gemm(const unsigned short* __restrict__ Eh, const unsigned short* __restrict__ El,
              const unsigned short* __restrict__ Wbase,
              unsigned short* __restrict__ Qh, unsigned short* __restrict__ Ql,
              unsigned short* __restrict__ Kh, unsigned short* __restrict__ Kl,
              unsigned short* __restrict__ Vt)
{
    // bid in [0,1152): xcd = bid&7 owns m-strips [8*xcd, 8*xcd+8)
    const int bid = blockIdx.x;
    const int xcd = bid & 7, j = bid >> 3;        // j in [0,144)
    const int mblk = xcd * 8 + (j / 18);          // 0..63
    const int rest = j % 18;
    const int nblk = rest % 6, z = rest / 6;

    const unsigned short* __restrict__ Wh = Wbase + (size_t)z * 2 * (EDIM * EDIM);
    const unsigned short* __restrict__ Wl = Wh + (EDIM * EDIM);

    __shared__ unsigned short Ahq[4][128][8], Alq[4][128][8];
    __shared__ unsigned short Bhq[4][128][8], Blq[4][128][8];

    const int t = threadIdx.x;
    const int wave = t >> 6, lane = t & 63;
    const int quad = lane >> 4, l16 = lane & 15;
    const int wm = (wave >> 1) * 64, wn = (wave & 1) * 64;
    const int m0 = mblk * 128, n0 = nblk * 128;

    const int sr = t >> 1, q0 = (t & 1) * 2;   // staging: row, first quad

    f4 acc[4][4];
#pragma unroll
    for (int i = 0; i < 4; i++)
#pragma unroll
        for (int j2 = 0; j2 < 4; j2++) acc[i][j2] = (f4){0.f, 0.f, 0.f, 0.f};

    for (int k0 = 0; k0 < EDIM; k0 += 32) {
        const size_t ao = (size_t)(m0 + sr) * EDIM + k0 + q0 * 8;
        const size_t bo = (size_t)(n0 + sr) * EDIM + k0 + q0 * 8;
        us8 a0 = *(const us8*)&Eh[ao], a1 = *(const us8*)&Eh[ao + 8];
        us8 b0 = *(const us8*)&Wh[bo], b1 = *(const us8*)&Wh[bo + 8];
        us8 a2, a3, b2, b3;
        if (z != 2) {
            a2 = *(const us8*)&El[ao]; a3 = *(const us8*)&El[ao + 8];
            b2 = *(const us8*)&Wl[bo]; b3 = *(const us8*)&Wl[bo + 8];
        }
        __syncthreads();
        *(us8*)&Ahq[q0][sr][0] = a0; *(us8*)&Ahq[q0 + 1][sr][0] = a1;
        *(us8*)&Bhq[q0][sr][0] = b0; *(us8*)&Bhq[q0 + 1][sr][0] = b1;
        if (z != 2) {
            *(us8*)&Alq[q0][sr][0] = a2; *(us8*)&Alq[q0 + 1][sr][0] = a3;
            *(us8*)&Blq[q0][sr][0] = b2; *(us8*)&Blq[q0 + 1][sr][0] = b3;
        }
        __syncthreads();

        bh8 aH[4], bH[4];
#pragma unroll
        for (int mt = 0; mt < 4; mt++)
            aH[mt] = *(const bh8*)&Ahq[quad][wm + mt * 16 + l16][0];
#pragma unroll
        for (int nt = 0; nt < 4; nt++)
            bH[nt] = *(const bh8*)&Bhq[quad][wn + nt * 16 + l16][0];

        if (z != 2) {
            bh8 aL[4], bL[4];
#pragma unroll
            for (int mt = 0; mt < 4; mt++)
                aL[mt] = *(const bh8*)&Alq[quad][wm + mt * 16 + l16][0];
#pragma unroll
            for (int nt = 0; nt < 4; nt++)
                bL[nt] = *(const bh8*)&Blq[quad][wn + nt * 16 + l16][0];
#pragma unroll
            for (int mt = 0; mt < 4; mt++)
#pragma unroll
                for (int nt = 0; nt < 4; nt++) {
                    acc[mt][nt] = MFMA(aH[mt], bH[nt], acc[mt][nt]);
                    acc[mt][nt] = MFMA(aH[mt], bL[nt], acc[mt][nt]);
                    acc[mt][nt] = MFMA(aL[mt], bH[nt], acc[mt][nt]);
                }
        } else {
#pragma unroll
            for (int mt = 0; mt < 4; mt++)
#pragma unroll
                for (int nt = 0; nt < 4; nt++)
                    acc[mt][nt] = MFMA(aH[mt], bH[nt], acc[mt][nt]);
        }
    }

    // epilogue: C/D layout col=lane&15, row=quad*4+reg
#pragma unroll
    for (int mt = 0; mt < 4; mt++)
#pragma unroll
        for (int nt = 0; nt < 4; nt++)
#pragma unroll
            for (int r = 0; r < 4; r++) {
                int row = m0 + wm + mt * 16 + quad * 4 + r;
                int col = n0 + wn + nt * 16 + l16;
                float v = acc[mt][nt][r];
                if (z == 2) {
                    int bb = row >> 10, nr = row & 1023;
                    int g = nr * 12 + (col >> 6);          // 768 = 12*64
                    int hh = g >> 10, key = g & 1023, dim = col & 63;
                    Vt[(((size_t)(bb * NH + hh)) * DH + dim) * NSEQ + key] = f2bf(v);
                } else {
                    unsigned short h = f2bf(v);
                    unsigned short l = f2bf(v - bf2f(h));
                    size_t o = (size_t)row * EDIM + col;
                    if (z == 0) { Qh[o] = h; Ql[o] = l; }
                    else        { Kh[o] = h; Kl[o] = l; }
                }
            }
}

// ---------------------------------------------------------------------------
// Flash attention, MFMA. XCD swizzle clusters blocks by HEAD so each XCD's
// L2 serves the head's 4 MB bias slab across batches/row-tiles.
// ---------------------------------------------------------------------------
__global__ __launch_bounds__(256)
void attn_mfma(const unsigned short* __restrict__ Qh, const unsigned short* __restrict__ Ql,
               const unsigned short* __restrict__ Kh, const unsigned short* __restrict__ Kl,
               const unsigned short* __restrict__ Vt, const float* __restrict__ Bm,
               unsigned short* __restrict__ Hc)
{
    // bid in [0,1536): xcd = bid&7; 12 (h,b) combos per xcd, clustered by h.
    const int bid = blockIdx.x;
    const int xcd = bid & 7, j = bid >> 3;        // j in [0,192)
    const int combo = xcd * 12 + (j >> 4);        // 0..95, consecutive = same h
    const int rt = j & 15;
    const int h = combo >> 3, b = combo & 7;
    const int r0 = rt * 64;

    __shared__ unsigned short Qhs[64][72], Qls[64][72];
    __shared__ unsigned short Khs[64][72], Kls[64][72];
    __shared__ unsigned short Vts[64][72];          // [dim][key]
    __shared__ unsigned short Ps[4][16][72];        // per-wave P tile [row][key]

    const int t = threadIdx.x;
    const int wave = t >> 6, lane = t & 63;
    const int quad = lane >> 4, l16 = lane & 15;
    const int wr = wave * 16;

    const int srow = t >> 2, sseg = (t & 3) * 16;

    const size_t hb = (size_t)b * (NSEQ * EDIM) + (size_t)h * (NSEQ * DH);
    const size_t vb = (((size_t)(b * NH + h)) * DH) * NSEQ;

    // stage Q tile
    {
        const size_t qo = hb + (size_t)(r0 + srow) * DH + sseg;
        us8 q0 = *(const us8*)&Qh[qo], q1 = *(const us8*)&Qh[qo + 8];
        us8 q2 = *(const us8*)&Ql[qo], q3 = *(const us8*)&Ql[qo + 8];
        *(us8*)&Qhs[srow][sseg] = q0; *(us8*)&Qhs[srow][sseg + 8] = q1;
        *(us8*)&Qls[srow][sseg] = q2; *(us8*)&Qls[srow][sseg + 8] = q3;
    }

    float m[4] = {-3e38f, -3e38f, -3e38f, -3e38f};
    float lsum[4] = {0.f, 0.f, 0.f, 0.f};
    f4 o[4];
#pragma unroll
    for (int dt = 0; dt < 4; dt++) o[dt] = (f4){0.f, 0.f, 0.f, 0.f};

    bh8 qfh[2], qfl[2];
    const float* bb = Bm + ((size_t)h << 20) + ((size_t)(r0 + wr + quad * 4) << 10) + l16;

    for (int kt = 0; kt < 16; kt++) {
        const int c0 = kt * 64;
        const size_t ko = hb + (size_t)(c0 + srow) * DH + sseg;
        const size_t vo = vb + (size_t)srow * NSEQ + c0 + sseg;
        us8 k0v = *(const us8*)&Kh[ko], k1v = *(const us8*)&Kh[ko + 8];
        us8 k2v = *(const us8*)&Kl[ko], k3v = *(const us8*)&Kl[ko + 8];
        us8 v0v = *(const us8*)&Vt[vo], v1v = *(const us8*)&Vt[vo + 8];
        __syncthreads();
        *(us8*)&Khs[srow][sseg] = k0v; *(us8*)&Khs[srow][sseg + 8] = k1v;
        *(us8*)&Kls[srow][sseg] = k2v; *(us8*)&Kls[srow][sseg + 8] = k3v;
        *(us8*)&Vts[srow][sseg] = v0v; *(us8*)&Vts[srow][sseg + 8] = v1v;
        __syncthreads();

        if (kt == 0) {
#pragma unroll
            for (int ks = 0; ks < 2; ks++) {
                qfh[ks] = *(const bh8*)&Qhs[wr + l16][ks * 32 + quad * 8];
                qfl[ks] = *(const bh8*)&Qls[wr + l16][ks * 32 + quad * 8];
            }
        }

        // ---- scores ----
        f4 s[4];
#pragma unroll
        for (int ct = 0; ct < 4; ct++) {
            bh8 kh0 = *(const bh8*)&Khs[ct * 16 + l16][quad * 8];
            bh8 kh1 = *(const bh8*)&Khs[ct * 16 + l16][32 + quad * 8];
            bh8 kl0 = *(const bh8*)&Kls[ct * 16 + l16][quad * 8];
            bh8 kl1 = *(const bh8*)&Kls[ct * 16 + l16][32 + quad * 8];
            f4 a = (f4){0.f, 0.f, 0.f, 0.f};
            a = MFMA(qfh[0], kh0, a); a = MFMA(qfh[1], kh1, a);
            a = MFMA(qfl[0], kh0, a); a = MFMA(qfl[1], kh1, a);
            a = MFMA(qfh[0], kl0, a); a = MFMA(qfh[1], kl1, a);
            s[ct] = a;
        }
#pragma unroll
        for (int ct = 0; ct < 4; ct++)
#pragma unroll
            for (int r = 0; r < 4; r++)
                s[ct][r] = fmaf(s[ct][r], 0.125f, bb[(size_t)r * NSEQ + c0 + ct * 16]);

        // ---- online softmax ----
        float alpha[4];
#pragma unroll
        for (int r = 0; r < 4; r++) {
            float mx = fmaxf(fmaxf(s[0][r], s[1][r]), fmaxf(s[2][r], s[3][r]));
            mx = fmaxf(mx, __shfl_xor(mx, 1));
            mx = fmaxf(mx, __shfl_xor(mx, 2));
            mx = fmaxf(mx, __shfl_xor(mx, 4));
            mx = fmaxf(mx, __shfl_xor(mx, 8));
            float mn = fmaxf(m[r], mx);
            alpha[r] = __expf(m[r] - mn);
            m[r] = mn;
        }
#pragma unroll
        for (int ct = 0; ct < 4; ct++)
#pragma unroll
            for (int r = 0; r < 4; r++)
                s[ct][r] = __expf(s[ct][r] - m[r]);
#pragma unroll
        for (int r = 0; r < 4; r++) {
            float ls = s[0][r] + s[1][r] + s[2][r] + s[3][r];
            ls += __shfl_xor(ls, 1);
            ls += __shfl_xor(ls, 2);
            ls += __shfl_xor(ls, 4);
            ls += __shfl_xor(ls, 8);
            lsum[r] = lsum[r] * alpha[r] + ls;
        }
#pragma unroll
        for (int dt = 0; dt < 4; dt++)
#pragma unroll
            for (int r = 0; r < 4; r++) o[dt][r] *= alpha[r];

        // ---- P -> bf16 -> LDS (C-layout -> A-layout) ----
#pragma unroll
        for (int ct = 0; ct < 4; ct++)
#pragma unroll
            for (int r = 0; r < 4; r++)
                Ps[wave][quad * 4 + r][ct * 16 + l16] = f2bf(s[ct][r]);

        bh8 p0 = *(const bh8*)&Ps[wave][l16][quad * 8];
        bh8 p1 = *(const bh8*)&Ps[wave][l16][32 + quad * 8];
#pragma unroll
        for (int dt = 0; dt < 4; dt++) {
            bh8 v0 = *(const bh8*)&Vts[dt * 16 + l16][quad * 8];
            bh8 v1 = *(const bh8*)&Vts[dt * 16 + l16][32 + quad * 8];
            o[dt] = MFMA(p0, v0, o[dt]);
            o[dt] = MFMA(p1, v1, o[dt]);
        }
    }

    // epilogue
#pragma unroll
    for (int r = 0; r < 4; r++) lsum[r] = 1.f / lsum[r];
#pragma unroll
    for (int dt = 0; dt < 4; dt++)
#pragma unroll
        for (int r = 0; r < 4; r++) {
            int row = r0 + wr + quad * 4 + r;
            int col = h * DH + dt * 16 + l16;
            Hc[(size_t)(b * NSEQ + row) * EDIM + col] = f2bf(o[dt][r] * lsum[r]);
        }
}

// ---------------------------------------------------------------------------
// Output projection: out = Hc_bf16 @ WO, 1-term MFMA, quad-major LDS,
// XCD swizzle (6 n-siblings of an A-strip share an XCD).
// ---------------------------------------------------------------------------
__global__ __launch_bounds__(256)
void out_gemm(const unsigned short* __restrict__ A, const unsigned short* __restrict__ Wh,
              float* __restrict__ C)
{
    const int bid = blockIdx.x;                  // [0,384)
    const int xcd = bid & 7, j = bid >> 3;       // j in [0,48)
    const int mblk = xcd * 8 + (j / 6);          // 0..63
    const int nblk = j % 6;

    __shared__ unsigned short Ahq[4][128][8];
    __shared__ unsigned short Bhq[4][128][8];

    const int t = threadIdx.x;
    const int wave = t >> 6, lane = t & 63;
    const int quad = lane >> 4, l16 = lane & 15;
    const int wm = (wave >> 1) * 64, wn = (wave & 1) * 64;
    const int m0 = mblk * 128, n0 = nblk * 128;
    const int sr = t >> 1, q0 = (t & 1) * 2;

    f4 acc[4][4];
#pragma unroll
    for (int i = 0; i < 4; i++)
#pragma unroll
        for (int j2 = 0; j2 < 4; j2++) acc[i][j2] = (f4){0.f, 0.f, 0.f, 0.f};

    for (int k0 = 0; k0 < EDIM; k0 += 32) {
        const size_t ao = (size_t)(m0 + sr) * EDIM + k0 + q0 * 8;
        const size_t bo = (size_t)(n0 + sr) * EDIM + k0 + q0 * 8;
        us8 a0 = *(const us8*)&A[ao], a1 = *(const us8*)&A[ao + 8];
        us8 b0 = *(const us8*)&Wh[bo], b1 = *(const us8*)&Wh[bo + 8];
        __syncthreads();
        *(us8*)&Ahq[q0][sr][0] = a0; *(us8*)&Ahq[q0 + 1][sr][0] = a1;
        *(us8*)&Bhq[q0][sr][0] = b0; *(us8*)&Bhq[q0 + 1][sr][0] = b1;
        __syncthreads();

        bh8 aF[4], bF[4];
#pragma unroll
        for (int mt = 0; mt < 4; mt++)
            aF[mt] = *(const bh8*)&Ahq[quad][wm + mt * 16 + l16][0];
#pragma unroll
        for (int nt = 0; nt < 4; nt++)
            bF[nt] = *(const bh8*)&Bhq[quad][wn + nt * 16 + l16][0];
#pragma unroll
        for (int mt = 0; mt < 4; mt++)
#pragma unroll
            for (int nt = 0; nt < 4; nt++)
                acc[mt][nt] = MFMA(aF[mt], bF[nt], acc[mt][nt]);
    }

#pragma unroll
    for (int mt = 0; mt < 4; mt++)
#pragma unroll
        for (int nt = 0; nt < 4; nt++)
#pragma unroll
            for (int r = 0; r < 4; r++) {
                int row = m0 + wm + mt * 16 + quad * 4 + r;
                int col = n0 + wn + nt * 16 + l16;
                C[(size_t)row * EDIM + col] = acc[mt][nt][r];
            }
}

// ---------------------------------------------------------------------------
extern "C" void kernel_launch(void* const* d_in, const int* in_sizes, int n_in,
                              void* d_out, int out_size, void* d_ws, size_t ws_size,
                              hipStream_t stream)
{
    const float* emb = (const float*)d_in[0];
    const float* Bm  = (const float*)d_in[1];
    const float* WQ  = (const float*)d_in[2];
    const float* WK  = (const float*)d_in[3];
    const float* WV  = (const float*)d_in[4];
    const float* WO  = (const float*)d_in[5];
    float* out = (float*)d_out;

    const size_t SZ = (size_t)NB * NSEQ * EDIM;        // 6,291,456 elements
    const size_t WSZ = (size_t)EDIM * EDIM;            // 589,824

    unsigned short* p  = (unsigned short*)d_ws;
    unsigned short* Eh = p;                  p += SZ;   // later reused as Hc
    unsigned short* El = p;                  p += SZ;
    unsigned short* Wb = p;                  p += 8 * WSZ;  // WQ h/l, WK h/l, WV h/l, WO h/l
    unsigned short* Qh = p;                  p += SZ;
    unsigned short* Ql = p;                  p += SZ;
    unsigned short* Kh = p;                  p += SZ;
    unsigned short* Kl = p;                  p += SZ;
    unsigned short* Vt = p;                  p += SZ;
    unsigned short* Hc = Eh;                 // alias: emb-hi dead after qkv_gemm

    // 1) conversions
    conv_emb<<<dim3(SZ / (256 * 4)), dim3(256), 0, stream>>>(emb, Eh, El);
    conv_w<<<dim3(EDIM / 64, EDIM / 64, 4), dim3(256), 0, stream>>>(WQ, WK, WV, WO, Wb);

    // 2) QKV projection (Q/K 3-term, V 1-term), XCD-swizzled 1D grid
    qkv_gemm<<<dim3(1152), dim3(256), 0, stream>>>(
        Eh, El, Wb, Qh, Ql, Kh, Kl, Vt);

    // 3) flash attention, XCD-swizzled 1D grid
    attn_mfma<<<dim3(1536), dim3(256), 0, stream>>>(
        Qh, Ql, Kh, Kl, Vt, Bm, Hc);

    // 4) output projection, XCD-swizzled 1D grid
    out_gemm<<<dim3(384), dim3(256), 0, stream>>>(
        Hc, Wb + 6 * WSZ, out);
}